// Round 17
// baseline (454.936 us; speedup 1.0000x reference)
//
#include <hip/hip_runtime.h>
#include <hip/hip_bf16.h>

typedef __attribute__((ext_vector_type(8))) short short8;
typedef __attribute__((ext_vector_type(8))) _Float16 half8;
typedef __attribute__((ext_vector_type(4))) float f32x4;

#define DEV __device__ __forceinline__

DEV short f2h(float f) { _Float16 h = (_Float16)f; return __builtin_bit_cast(short, h); }
DEV float h2f(short s) { return (float)__builtin_bit_cast(_Float16, s); }
DEV void split2h(float v, short& hi, short& lo) {
    _Float16 h = (_Float16)v; hi = __builtin_bit_cast(short, h);
    _Float16 l = (_Float16)(v - (float)h); lo = __builtin_bit_cast(short, l);
}
DEV float frcp(float x) { return __builtin_amdgcn_rcpf(x); }          // v_rcp_f32, ~1 ulp
DEV float sigm(float x) { return frcp(1.f + __expf(-x)); }
DEV float tanh_(float x) { return 1.f - 2.f * frcp(__expf(2.f * x) + 1.f); }
DEV int swz(int r, int kb) { return kb ^ ((r & 7) << 4); }  // byte offset within row

// ---------------- init ----------------
__global__ void k_init(int* degi, int* dego, float* logsum, int n) {
    int i = blockIdx.x * blockDim.x + threadIdx.x;
    int st = gridDim.x * blockDim.x;
    for (int k = i; k < n; k += st) { degi[k] = 0; dego[k] = 0; }
    if (i == 0) *logsum = 0.f;
}

// ---------------- fp32 -> split fp16 (hi + lo residual) weight prep ----------------
// layout: [0,12288) gru_Wih | [12288,24576) gru_Whh | [24576,40960) lstm_Wih
//         [40960,57344) lstm_Whh | [57344,73728) pna_W
__global__ void k_prep(const float* __restrict__ a, const float* __restrict__ b,
                       const float* __restrict__ c, const float* __restrict__ d,
                       const float* __restrict__ e, short* __restrict__ ohi,
                       short* __restrict__ olo) {
    int i = blockIdx.x * 256 + threadIdx.x;
    float v;
    if (i < 12288) v = a[i];
    else if (i < 24576) v = b[i - 12288];
    else if (i < 40960) v = c[i - 24576];
    else if (i < 57344) v = d[i - 40960];
    else if (i < 73728) v = e[i - 57344];
    else return;
    short hi, lo; split2h(v, hi, lo);
    ohi[i] = hi; olo[i] = lo;
}

// ---------------- GRU messages -> msg[E][64] fp32, + degree counts ----------------
// persistent (512,1) grid 256, 128-edge tiles; fp16 weights resident; T14 prefetch
__global__ __launch_bounds__(512, 1) void k_gru(
    const int* __restrict__ src, const int* __restrict__ dst, const int* __restrict__ etype,
    const float* __restrict__ efeat, const float* __restrict__ nfeat, const float* __restrict__ rel_emb,
    const float* __restrict__ bih, const float* __restrict__ bhh,
    const short* __restrict__ whi,
    float* __restrict__ msg, int* __restrict__ degi, int* __restrict__ dego, int ntiles) {
    __shared__ short xs[128 * 64];   // x fp16
    __shared__ short hs[128 * 64];   // h fp16
    __shared__ short wh_s[384 * 64]; // fp16 weights: rows 0..191 Wih, 192..383 Whh
    int tid = threadIdx.x;
    for (int i = 0; i < 6; ++i) {    // stage weights (3072 short8)
        int q = i * 512 + tid;
        short8 v = ((const short8*)whi)[q];
        int r = q >> 3; int kb = (q & 7) * 16;
        *(short8*)((char*)wh_s + r * 128 + swz(r, kb)) = v;
    }

    int lane = tid & 63, w = tid >> 6;
    int col = lane & 15, rgrp = lane >> 4;
    int rowb = w * 16;
    int arow = rowb + col;
    int kl = rgrp * 8;
    int el = tid >> 2; int d0s = (tid & 3) * 16;
    f32x4 z4 = {0.f, 0.f, 0.f, 0.f};
    float birv[4], bizv[4], binv[4], bhrv[4], bhzv[4], bhnv[4];
    for (int t = 0; t < 4; ++t) {
        int d = t * 16 + col;
        birv[t] = bih[d];       bhrv[t] = bhh[d];
        bizv[t] = bih[64 + d];  bhzv[t] = bhh[64 + d];
        binv[t] = bih[128 + d]; bhnv[t] = bhh[128 + d];
    }

    // prefetch registers (named, rule-#20-safe)
    f32x4 pa0, pa1, pa2, pa3, pr0, pr1, pr2, pr3, ph0, ph1, ph2, ph3;
    {   // prologue: load first tile
        int e = blockIdx.x * 128 + el;
        int et = etype[e]; int sv = src[e];
        const float* ef = efeat + (size_t)e * 64 + d0s;
        const float* re = rel_emb + et * 64 + d0s;
        const float* nf = nfeat + (size_t)sv * 64 + d0s;
        pa0 = *(const f32x4*)ef;       pa1 = *(const f32x4*)(ef + 4);
        pa2 = *(const f32x4*)(ef + 8); pa3 = *(const f32x4*)(ef + 12);
        pr0 = *(const f32x4*)re;       pr1 = *(const f32x4*)(re + 4);
        pr2 = *(const f32x4*)(re + 8); pr3 = *(const f32x4*)(re + 12);
        ph0 = *(const f32x4*)nf;       ph1 = *(const f32x4*)(nf + 4);
        ph2 = *(const f32x4*)(nf + 8); ph3 = *(const f32x4*)(nf + 12);
    }

    for (int tile = blockIdx.x; tile < ntiles; tile += gridDim.x) {
        int base = tile * 128;
        {   // LDS-write phase from prefetched regs
            short8 sx0, sx1, sh0, sh1;
            for (int j = 0; j < 4; ++j) {
                sx0[j] = f2h(pa0[j] + pr0[j]); sx0[4 + j] = f2h(pa1[j] + pr1[j]);
                sx1[j] = f2h(pa2[j] + pr2[j]); sx1[4 + j] = f2h(pa3[j] + pr3[j]);
                sh0[j] = f2h(ph0[j]);          sh0[4 + j] = f2h(ph1[j]);
                sh1[j] = f2h(ph2[j]);          sh1[4 + j] = f2h(ph3[j]);
            }
            int kb0 = d0s * 2, kb1 = (d0s + 8) * 2;
            *(short8*)((char*)xs + el * 128 + swz(el, kb0)) = sx0;
            *(short8*)((char*)xs + el * 128 + swz(el, kb1)) = sx1;
            *(short8*)((char*)hs + el * 128 + swz(el, kb0)) = sh0;
            *(short8*)((char*)hs + el * 128 + swz(el, kb1)) = sh1;
            if (tid < 128) {
                int e2 = base + tid;
                atomicAdd(&degi[dst[e2]], 1);
                atomicAdd(&dego[src[e2]], 1);
            }
        }
        __syncthreads();
        int nt = tile + gridDim.x;
        if (nt < ntiles) {   // prefetch next tile: latency hides under MFMA+epilogue
            int e = nt * 128 + el;
            int et = etype[e]; int sv = src[e];
            const float* ef = efeat + (size_t)e * 64 + d0s;
            const float* re = rel_emb + et * 64 + d0s;
            const float* nf = nfeat + (size_t)sv * 64 + d0s;
            pa0 = *(const f32x4*)ef;       pa1 = *(const f32x4*)(ef + 4);
            pa2 = *(const f32x4*)(ef + 8); pa3 = *(const f32x4*)(ef + 12);
            pr0 = *(const f32x4*)re;       pr1 = *(const f32x4*)(re + 4);
            pr2 = *(const f32x4*)(re + 8); pr3 = *(const f32x4*)(re + 12);
            ph0 = *(const f32x4*)nf;       ph1 = *(const f32x4*)(nf + 4);
            ph2 = *(const f32x4*)(nf + 8); ph3 = *(const f32x4*)(nf + 12);
        }

        f32x4 gi[12], gh[12];
        for (int t = 0; t < 12; ++t) { gi[t] = z4; gh[t] = z4; }
        for (int ks = 0; ks < 2; ++ks) {
            int kb = (ks * 32 + kl) * 2;
            half8 xf = *(half8*)((char*)xs + arow * 128 + swz(arow, kb));
            half8 hf = *(half8*)((char*)hs + arow * 128 + swz(arow, kb));
#pragma unroll
            for (int ct = 0; ct < 12; ++ct) {
                int wr = ct * 16 + col;
                half8 wah = *(half8*)((char*)wh_s + wr * 128 + swz(wr, kb));
                half8 wbh = *(half8*)((char*)wh_s + (192 + wr) * 128 + swz(192 + wr, kb));
                gi[ct] = __builtin_amdgcn_mfma_f32_16x16x32_f16(xf, wah, gi[ct], 0, 0, 0);
                gh[ct] = __builtin_amdgcn_mfma_f32_16x16x32_f16(hf, wbh, gh[ct], 0, 0, 0);
            }
        }
        __syncthreads();   // all LDS reads done; next iteration may overwrite

        int se[4];
        for (int j = 0; j < 4; ++j) se[j] = src[base + rowb + rgrp * 4 + j];
        for (int t = 0; t < 4; ++t) {
            int d = t * 16 + col;
            for (int j = 0; j < 4; ++j) {
                int el2 = rowb + rgrp * 4 + j;
                float hv = nfeat[(size_t)se[j] * 64 + d];   // fp32 exact (L2-hot)
                float r = sigm(gi[t][j] + birv[t] + gh[t][j] + bhrv[t]);
                float z = sigm(gi[t + 4][j] + bizv[t] + gh[t + 4][j] + bhzv[t]);
                float n = tanh_(gi[t + 8][j] + binv[t] + r * (gh[t + 8][j] + bhnv[t]));
                float m = (1.f - z) * n + z * hv;
                msg[(size_t)(base + el2) * 64 + d] = m;
            }
        }
    }
}

// ---------------- parallel exclusive scan of degi -> offs, cursor --------------
__global__ void k_scan1(const int* __restrict__ degi, int* __restrict__ bsum, int n) {
    __shared__ int red[256];
    int i = blockIdx.x * 256 + threadIdx.x;
    red[threadIdx.x] = (i < n) ? degi[i] : 0;
    __syncthreads();
    for (int off = 128; off > 0; off >>= 1) {
        if (threadIdx.x < off) red[threadIdx.x] += red[threadIdx.x + off];
        __syncthreads();
    }
    if (threadIdx.x == 0) bsum[blockIdx.x] = red[0];
}
__global__ void k_scan2(int* __restrict__ bsum, int nb) {
    __shared__ int part[1024];
    int tid = threadIdx.x;
    int orig = (tid < nb) ? bsum[tid] : 0;
    part[tid] = orig;
    __syncthreads();
    for (int off = 1; off < 1024; off <<= 1) {
        int t = (tid >= off) ? part[tid - off] : 0;
        __syncthreads();
        part[tid] += t;
        __syncthreads();
    }
    if (tid < nb) bsum[tid] = part[tid] - orig;   // exclusive block prefix
}
__global__ void k_scan3(const int* __restrict__ degi, const int* __restrict__ bsum,
                        int* __restrict__ offs, int* __restrict__ cursor, int n) {
    __shared__ int part[256];
    int tid = threadIdx.x;
    int i = blockIdx.x * 256 + tid;
    int v = (i < n) ? degi[i] : 0;
    part[tid] = v;
    __syncthreads();
    for (int off = 1; off < 256; off <<= 1) {
        int t = (tid >= off) ? part[tid - off] : 0;
        __syncthreads();
        part[tid] += t;
        __syncthreads();
    }
    int excl = part[tid] - v + bsum[blockIdx.x];
    if (i < n) { offs[i] = excl; cursor[i] = excl; }
    if (i == n - 1) offs[n] = excl + v;
}

// ---------------- scatter edge ids into CSR buckets ----------------
__global__ void k_scatter(const int* __restrict__ dst, int* __restrict__ cursor,
                          int* __restrict__ idx, int E) {
    int e = blockIdx.x * 256 + threadIdx.x;
    if (e < E) {
        int p = atomicAdd(&cursor[dst[e]], 1);
        idx[p] = e;
    }
}

// ---------------- avg log out-degree: deterministic two-stage reduction ----------
__global__ void k_avgd(const int* __restrict__ dego, float* __restrict__ partial, int n) {
    __shared__ float red[256];
    int i = blockIdx.x * blockDim.x + threadIdx.x;
    float s = 0.f;
    for (int k = i; k < n; k += gridDim.x * blockDim.x) s += __logf((float)dego[k] + 1.f);
    red[threadIdx.x] = s;
    __syncthreads();
    for (int off = 128; off > 0; off >>= 1) {
        if (threadIdx.x < off) red[threadIdx.x] += red[threadIdx.x + off];
        __syncthreads();
    }
    if (threadIdx.x == 0) partial[blockIdx.x] = red[0];
}
__global__ void k_avgd2(const float* __restrict__ partial, float* __restrict__ logsum, int m) {
    if (threadIdx.x == 0 && blockIdx.x == 0) {
        float s = 0.f;
        for (int i = 0; i < m; ++i) s += partial[i];   // fixed order -> deterministic
        *logsum = s;
    }
}

// ---------------- PNA: CSR gather stats (f64 sums), dual-resident weights, LN ------
__global__ __launch_bounds__(256, 1) void k_pna(
    const float* __restrict__ msg, const int* __restrict__ offs, const int* __restrict__ idx,
    const float* __restrict__ logsum,
    const short* __restrict__ wphi, const short* __restrict__ wplo,
    const float* __restrict__ pnab,
    const float* __restrict__ lng, const float* __restrict__ lnb,
    float* __restrict__ nfnew, float* __restrict__ out1, int N) {
    __shared__ short agg[64 * 256];
    __shared__ short agl[64 * 256];
    __shared__ short wp[64 * 256];   // hi weights
    __shared__ short wpl[64 * 256];  // lo weights (resident together -> no restage)
    __shared__ float scl[64];
    int tid = threadIdx.x; int nb = blockIdx.x * 64;
    float avgd = logsum[0] / (float)N;
    f32x4 z4 = {0.f, 0.f, 0.f, 0.f};
    {
        int il = tid >> 2; int node = nb + il; int d0 = (tid & 3) * 16;
        if (node < N) {
            int o0 = offs[node], o1 = offs[node + 1];
            int dg = o1 - o0;
            double sm[16], sq[16];
            f32x4 mx[4], mn[4];
#pragma unroll
            for (int k = 0; k < 16; ++k) { sm[k] = 0.0; sq[k] = 0.0; }
#pragma unroll
            for (int q = 0; q < 4; ++q) {
                mx[q] = (f32x4){-1e30f, -1e30f, -1e30f, -1e30f};
                mn[q] = (f32x4){1e30f, 1e30f, 1e30f, 1e30f};
            }
            for (int i = o0; i < o1; ++i) {
                int e = idx[i];
                const float* mrow = msg + (size_t)e * 64 + d0;
#pragma unroll
                for (int q = 0; q < 4; ++q) {
                    f32x4 v = *(const f32x4*)(mrow + q * 4);
#pragma unroll
                    for (int j = 0; j < 4; ++j) {
                        double dv = (double)v[j];
                        sm[q * 4 + j] += dv;
                        sq[q * 4 + j] += dv * dv;
                        mx[q][j] = fmaxf(mx[q][j], v[j]);
                        mn[q][j] = fminf(mn[q][j], v[j]);
                    }
                }
            }
            double inv = 1.0 / (double)max(dg, 1);
            bool has = dg > 0;
            for (int g = 0; g < 2; ++g) {
                short8 vm, vx, vn, vs, lm, lx, ln_, ls;
                for (int k = 0; k < 8; ++k) {
                    int kk = g * 8 + k; int q = kk >> 2, j = kk & 3;
                    double mean_d = sm[kk] * inv;
                    double var_d = sq[kk] * inv - mean_d * mean_d;
                    float mean = (float)mean_d;
                    float sd = sqrtf(fmaxf((float)var_d, 0.f) + 1e-5f);
                    float mxv = has ? mx[q][j] : 0.f;
                    float mnv = has ? mn[q][j] : 0.f;
                    short th, tl;
                    split2h(mean, th, tl); vm[k] = th; lm[k] = tl;
                    split2h(mxv, th, tl);  vx[k] = th; lx[k] = tl;
                    split2h(mnv, th, tl);  vn[k] = th; ln_[k] = tl;
                    split2h(sd, th, tl);   vs[k] = th; ls[k] = tl;
                }
                int kb = (d0 + g * 8) * 2;
                *(short8*)((char*)agg + il * 512 + swz(il, kb)) = vm;
                *(short8*)((char*)agg + il * 512 + swz(il, kb + 128)) = vx;
                *(short8*)((char*)agg + il * 512 + swz(il, kb + 256)) = vn;
                *(short8*)((char*)agg + il * 512 + swz(il, kb + 384)) = vs;
                *(short8*)((char*)agl + il * 512 + swz(il, kb)) = lm;
                *(short8*)((char*)agl + il * 512 + swz(il, kb + 128)) = lx;
                *(short8*)((char*)agl + il * 512 + swz(il, kb + 256)) = ln_;
                *(short8*)((char*)agl + il * 512 + swz(il, kb + 384)) = ls;
            }
            if ((tid & 3) == 0) scl[il] = __logf((float)dg + 1.f) / avgd;
        } else {
            short8 zz = {0, 0, 0, 0, 0, 0, 0, 0};
            for (int g = 0; g < 2; ++g) {
                int kb = (d0 + g * 8) * 2;
                for (int part = 0; part < 4; ++part) {
                    *(short8*)((char*)agg + il * 512 + swz(il, kb + part * 128)) = zz;
                    *(short8*)((char*)agl + il * 512 + swz(il, kb + part * 128)) = zz;
                }
            }
            if ((tid & 3) == 0) scl[il] = 0.f;
        }
    }
    for (int i = 0; i < 8; ++i) {
        int q = i * 256 + tid;   // 2048 short8 each
        int r = q >> 5; int kb = (q & 31) * 16;
        short8 vh = ((const short8*)wphi)[q];
        short8 vl = ((const short8*)wplo)[q];
        *(short8*)((char*)wp + r * 512 + swz(r, kb)) = vh;
        *(short8*)((char*)wpl + r * 512 + swz(r, kb)) = vl;
    }
    __syncthreads();

    int lane = tid & 63, w = tid >> 6;
    int col = lane & 15, rgrp = lane >> 4;
    int arow = w * 16 + col; int kl = rgrp * 8;
    f32x4 acc[4] = {z4, z4, z4, z4};
    for (int ks = 0; ks < 8; ++ks) {   // (A_hi + A_lo)*W_hi + A_hi*W_lo
        int kb = (ks * 32 + kl) * 2;
        half8 af = *(half8*)((char*)agg + arow * 512 + swz(arow, kb));
        half8 al = *(half8*)((char*)agl + arow * 512 + swz(arow, kb));
#pragma unroll
        for (int ct = 0; ct < 4; ++ct) {
            int wr = ct * 16 + col;
            half8 bh_ = *(half8*)((char*)wp + wr * 512 + swz(wr, kb));
            half8 bl_ = *(half8*)((char*)wpl + wr * 512 + swz(wr, kb));
            acc[ct] = __builtin_amdgcn_mfma_f32_16x16x32_f16(af, bh_, acc[ct], 0, 0, 0);
            acc[ct] = __builtin_amdgcn_mfma_f32_16x16x32_f16(al, bh_, acc[ct], 0, 0, 0);
            acc[ct] = __builtin_amdgcn_mfma_f32_16x16x32_f16(af, bl_, acc[ct], 0, 0, 0);
        }
    }
    for (int j = 0; j < 4; ++j) {
        int il = w * 16 + rgrp * 4 + j; int node = nb + il;
        float sc = scl[il];
        float v[4]; float s = 0.f, s2 = 0.f;
        for (int ct = 0; ct < 4; ++ct) {
            int d = ct * 16 + col;
            float x = (acc[ct][j] + pnab[d]) * sc;
            v[ct] = x; s += x; s2 += x * x;
        }
        for (int m = 1; m < 16; m <<= 1) { s += __shfl_xor(s, m); s2 += __shfl_xor(s2, m); }
        float mean = s * (1.f / 64.f);
        float var = s2 * (1.f / 64.f) - mean * mean;
        float rstd = rsqrtf(var + 1e-5f);
        if (node < N) {
            for (int ct = 0; ct < 4; ++ct) {
                int d = ct * 16 + col;
                nfnew[(size_t)node * 64 + d] = v[ct];
                out1[(size_t)node * 64 + d] = (v[ct] - mean) * rstd * lng[d] + lnb[d];
            }
        }
    }
}

// ---------------- LSTM edge update + 2x LN ----------------
// persistent 1024-thread blocks, 256-edge tiles (128 KB LDS, 4 waves/SIMD); T14 prefetch
__global__ __launch_bounds__(1024, 4) void k_lstm(
    const int* __restrict__ dst, const float* __restrict__ efeat, const float* __restrict__ equery,
    const float* __restrict__ nfnew,
    const short* __restrict__ wlhi,
    const float* __restrict__ bih, const float* __restrict__ bhh,
    const float* __restrict__ lng, const float* __restrict__ lnb,
    float* __restrict__ out0, float* __restrict__ out2, int ntiles, int E) {
    __shared__ short ia[256 * 64];
    __shared__ short ea[256 * 64];
    __shared__ short wh_s[512 * 64];  // fp16: rows 0..255 Wih, 256..511 Whh
    int tid = threadIdx.x;
    for (int i = 0; i < 4; ++i) {
        int q = i * 1024 + tid;   // 4096 short8
        short8 v = ((const short8*)wlhi)[q];
        int r = q >> 3; int kb = (q & 7) * 16;
        *(short8*)((char*)wh_s + r * 128 + swz(r, kb)) = v;
    }

    int lane = tid & 63, w = tid >> 6;        // w in 0..15
    int col = lane & 15, rgrp = lane >> 4;
    int arow = w * 16 + col; int kl = rgrp * 8;
    int el = tid >> 2; int d0s = (tid & 3) * 16;
    f32x4 z4 = {0.f, 0.f, 0.f, 0.f};
    float bsi[4], bsf[4], bsg[4], bso[4], lngv[4], lnbv[4];
    for (int t = 0; t < 4; ++t) {
        int d = t * 16 + col;
        bsi[t] = bih[d] + bhh[d];
        bsf[t] = bih[64 + d] + bhh[64 + d];
        bsg[t] = bih[128 + d] + bhh[128 + d];
        bso[t] = bih[192 + d] + bhh[192 + d];
        lngv[t] = lng[d]; lnbv[t] = lnb[d];
    }

    f32x4 pi0, pi1, pi2, pi3, pe0, pe1, pe2, pe3;   // named prefetch regs
    {   // prologue: load first tile (guarded)
        int e = blockIdx.x * 256 + el;
        if (e < E) {
            int dv = dst[e];
            const float* ip = nfnew + (size_t)dv * 64 + d0s;
            const float* ep = efeat + (size_t)e * 64 + d0s;
            pi0 = *(const f32x4*)ip;       pi1 = *(const f32x4*)(ip + 4);
            pi2 = *(const f32x4*)(ip + 8); pi3 = *(const f32x4*)(ip + 12);
            pe0 = *(const f32x4*)ep;       pe1 = *(const f32x4*)(ep + 4);
            pe2 = *(const f32x4*)(ep + 8); pe3 = *(const f32x4*)(ep + 12);
        } else {
            pi0 = z4; pi1 = z4; pi2 = z4; pi3 = z4;
            pe0 = z4; pe1 = z4; pe2 = z4; pe3 = z4;
        }
    }

    for (int tile = blockIdx.x; tile < ntiles; tile += gridDim.x) {
        int base = tile * 256;
        {   // LDS-write phase from prefetched regs (zeros for OOB rows)
            short8 si0, si1, se0, se1;
            for (int j = 0; j < 4; ++j) {
                si0[j] = f2h(pi0[j]); si0[4 + j] = f2h(pi1[j]);
                si1[j] = f2h(pi2[j]); si1[4 + j] = f2h(pi3[j]);
                se0[j] = f2h(pe0[j]); se0[4 + j] = f2h(pe1[j]);
                se1[j] = f2h(pe2[j]); se1[4 + j] = f2h(pe3[j]);
            }
            int kb0 = d0s * 2, kb1 = (d0s + 8) * 2;
            *(short8*)((char*)ia + el * 128 + swz(el, kb0)) = si0;
            *(short8*)((char*)ia + el * 128 + swz(el, kb1)) = si1;
            *(short8*)((char*)ea + el * 128 + swz(el, kb0)) = se0;
            *(short8*)((char*)ea + el * 128 + swz(el, kb1)) = se1;
        }
        __syncthreads();
        int nt = tile + gridDim.x;
        if (nt < ntiles) {   // prefetch next tile (guarded)
            int e = nt * 256 + el;
            if (e < E) {
                int dv = dst[e];
                const float* ip = nfnew + (size_t)dv * 64 + d0s;
                const float* ep = efeat + (size_t)e * 64 + d0s;
                pi0 = *(const f32x4*)ip;       pi1 = *(const f32x4*)(ip + 4);
                pi2 = *(const f32x4*)(ip + 8); pi3 = *(const f32x4*)(ip + 12);
                pe0 = *(const f32x4*)ep;       pe1 = *(const f32x4*)(ep + 4);
                pe2 = *(const f32x4*)(ep + 8); pe3 = *(const f32x4*)(ep + 12);
            } else {
                pi0 = z4; pi1 = z4; pi2 = z4; pi3 = z4;
                pe0 = z4; pe1 = z4; pe2 = z4; pe3 = z4;
            }
        }

        f32x4 acc[16];
        for (int t = 0; t < 16; ++t) acc[t] = z4;
        for (int ks = 0; ks < 2; ++ks) {
            int kb = (ks * 32 + kl) * 2;
            half8 fi = *(half8*)((char*)ia + arow * 128 + swz(arow, kb));
            half8 fe = *(half8*)((char*)ea + arow * 128 + swz(arow, kb));
#pragma unroll
            for (int ct = 0; ct < 16; ++ct) {
                int wr = ct * 16 + col;
                half8 wah = *(half8*)((char*)wh_s + wr * 128 + swz(wr, kb));
                half8 wbh = *(half8*)((char*)wh_s + (256 + wr) * 128 + swz(256 + wr, kb));
                acc[ct] = __builtin_amdgcn_mfma_f32_16x16x32_f16(fi, wah, acc[ct], 0, 0, 0);
                acc[ct] = __builtin_amdgcn_mfma_f32_16x16x32_f16(fe, wbh, acc[ct], 0, 0, 0);
            }
        }
        __syncthreads();   // all waves done reading ia/ea -> next iteration may overwrite

        for (int j = 0; j < 4; ++j) {
            size_t e = base + w * 16 + rgrp * 4 + j;
            if (e >= (size_t)E) continue;
            float hv[4], cv[4];
            float sh = 0.f, sh2 = 0.f, sc = 0.f, sc2 = 0.f;
            for (int t = 0; t < 4; ++t) {
                int d = t * 16 + col;
                float gi_ = acc[t][j] + bsi[t];
                float gf_ = acc[t + 4][j] + bsf[t];
                float gg_ = acc[t + 8][j] + bsg[t];
                float go_ = acc[t + 12][j] + bso[t];
                float eq = equery[e * 64 + d];
                float c = sigm(gf_) * eq + sigm(gi_) * tanh_(gg_);
                float h = sigm(go_) * tanh_(c);
                cv[t] = c; hv[t] = h;
                sh += h; sh2 += h * h; sc += c; sc2 += c * c;
            }
            for (int m = 1; m < 16; m <<= 1) {
                sh += __shfl_xor(sh, m); sh2 += __shfl_xor(sh2, m);
                sc += __shfl_xor(sc, m); sc2 += __shfl_xor(sc2, m);
            }
            float mh = sh * (1.f / 64.f), vh = sh2 * (1.f / 64.f) - mh * mh, rh = rsqrtf(vh + 1e-5f);
            float mc = sc * (1.f / 64.f), vc = sc2 * (1.f / 64.f) - mc * mc, rc = rsqrtf(vc + 1e-5f);
            for (int t = 0; t < 4; ++t) {
                int d = t * 16 + col;
                out0[e * 64 + d] = (hv[t] - mh) * rh * lngv[t] + lnbv[t];
                out2[e * 64 + d] = (cv[t] - mc) * rc * lngv[t] + lnbv[t];
            }
        }
    }
}

extern "C" void kernel_launch(void* const* d_in, const int* in_sizes, int n_in,
                              void* d_out, int out_size, void* d_ws, size_t ws_size,
                              hipStream_t stream) {
    const int* src = (const int*)d_in[0];
    const int* dst = (const int*)d_in[1];
    const int* etype = (const int*)d_in[2];
    const float* efeat = (const float*)d_in[3];
    const float* nfeat = (const float*)d_in[4];
    const float* equery = (const float*)d_in[5];
    const float* rel_emb = (const float*)d_in[6];
    const float* gWih = (const float*)d_in[7];
    const float* gWhh = (const float*)d_in[8];
    const float* gbih = (const float*)d_in[9];
    const float* gbhh = (const float*)d_in[10];
    const float* pW = (const float*)d_in[11];
    const float* pb = (const float*)d_in[12];
    const float* lWih = (const float*)d_in[13];
    const float* lWhh = (const float*)d_in[14];
    const float* lbih = (const float*)d_in[15];
    const float* lbhh = (const float*)d_in[16];
    const float* lng = (const float*)d_in[17];
    const float* lnb = (const float*)d_in[18];
    int E = in_sizes[0];
    int N = in_sizes[4] / 64;
    int ntiles = E / 128;
    int ntiles2 = (E + 255) / 256;
    int nb = (N + 255) / 256;

    char* p = (char*)d_ws;
    float* nfnew = (float*)p;     p += (size_t)N * 64 * 4;
    int* degi = (int*)p;          p += (size_t)N * 4;
    int* dego = (int*)p;          p += (size_t)N * 4;
    int* offs = (int*)p;          p += (size_t)(N + 1) * 4 + 252;  // keep 16B align downstream
    int* cursor = (int*)p;        p += (size_t)N * 4;
    int* idx = (int*)p;           p += (size_t)E * 4;
    float* logsum = (float*)p;    p += 256;
    float* partial = (float*)p;   p += 512;
    int* bsum = (int*)p;          p += 4096;
    short* wbf_hi = (short*)p;    p += 73728 * 2;
    short* wbf_lo = (short*)p;

    float* out0 = (float*)d_out;
    float* out1 = out0 + (size_t)E * 64;
    float* out2 = out1 + (size_t)N * 64;
    float* msg = out0;            // out0 region reused as msg scratch until k_lstm

    k_init<<<256, 256, 0, stream>>>(degi, dego, logsum, N);
    k_prep<<<288, 256, 0, stream>>>(gWih, gWhh, lWih, lWhh, pW, wbf_hi, wbf_lo);
    k_gru<<<256, 512, 0, stream>>>(src, dst, etype, efeat, nfeat, rel_emb, gbih, gbhh,
                                   wbf_hi, msg, degi, dego, ntiles);
    k_scan1<<<nb, 256, 0, stream>>>(degi, bsum, N);
    k_scan2<<<1, 1024, 0, stream>>>(bsum, nb);
    k_scan3<<<nb, 256, 0, stream>>>(degi, bsum, offs, cursor, N);
    k_scatter<<<(E + 255) / 256, 256, 0, stream>>>(dst, cursor, idx, E);
    k_avgd<<<128, 256, 0, stream>>>(dego, partial, N);
    k_avgd2<<<1, 64, 0, stream>>>(partial, logsum, 128);
    k_pna<<<(N + 63) / 64, 256, 0, stream>>>(msg, offs, idx, logsum,
                                             wbf_hi + 57344, wbf_lo + 57344, pb, lng, lnb,
                                             nfnew, out1, N);
    k_lstm<<<256, 1024, 0, stream>>>(dst, efeat, equery, nfnew,
                                     wbf_hi + 24576,
                                     lbih, lbhh, lng, lnb, out0, out2, ntiles2, E);
}

// Round 19
// 319.453 us; speedup vs baseline: 1.4241x; 1.4241x over previous
//
#include <hip/hip_runtime.h>
#include <hip/hip_bf16.h>

typedef __attribute__((ext_vector_type(8))) short short8;
typedef __attribute__((ext_vector_type(8))) _Float16 half8;
typedef __attribute__((ext_vector_type(4))) float f32x4;

#define DEV __device__ __forceinline__

DEV short f2h(float f) { _Float16 h = (_Float16)f; return __builtin_bit_cast(short, h); }
DEV float h2f(short s) { return (float)__builtin_bit_cast(_Float16, s); }
DEV void split2h(float v, short& hi, short& lo) {
    _Float16 h = (_Float16)v; hi = __builtin_bit_cast(short, h);
    _Float16 l = (_Float16)(v - (float)h); lo = __builtin_bit_cast(short, l);
}
DEV float frcp(float x) { return __builtin_amdgcn_rcpf(x); }          // v_rcp_f32, ~1 ulp
DEV float sigm(float x) { return frcp(1.f + __expf(-x)); }
DEV float tanh_(float x) { return 1.f - 2.f * frcp(__expf(2.f * x) + 1.f); }
DEV int swz(int r, int kb) { return kb ^ ((r & 7) << 4); }  // byte offset within row

// ---------------- init ----------------
__global__ void k_init(int* degi, int* dego, float* logsum, int n) {
    int i = blockIdx.x * blockDim.x + threadIdx.x;
    int st = gridDim.x * blockDim.x;
    for (int k = i; k < n; k += st) { degi[k] = 0; dego[k] = 0; }
    if (i == 0) *logsum = 0.f;
}

// ---------------- fp32 -> split fp16 (hi + lo residual) weight prep ----------------
// layout: [0,12288) gru_Wih | [12288,24576) gru_Whh | [24576,40960) lstm_Wih
//         [40960,57344) lstm_Whh | [57344,73728) pna_W
__global__ void k_prep(const float* __restrict__ a, const float* __restrict__ b,
                       const float* __restrict__ c, const float* __restrict__ d,
                       const float* __restrict__ e, short* __restrict__ ohi,
                       short* __restrict__ olo) {
    int i = blockIdx.x * 256 + threadIdx.x;
    float v;
    if (i < 12288) v = a[i];
    else if (i < 24576) v = b[i - 12288];
    else if (i < 40960) v = c[i - 24576];
    else if (i < 57344) v = d[i - 40960];
    else if (i < 73728) v = e[i - 57344];
    else return;
    short hi, lo; split2h(v, hi, lo);
    ohi[i] = hi; olo[i] = lo;
}

// ---------------- GRU messages -> msg[E][64] fp32, + degree counts ----------------
// persistent (512,1) grid 256, 128-edge tiles; fp16 weights resident; T14 prefetch
__global__ __launch_bounds__(512, 1) void k_gru(
    const int* __restrict__ src, const int* __restrict__ dst, const int* __restrict__ etype,
    const float* __restrict__ efeat, const float* __restrict__ nfeat, const float* __restrict__ rel_emb,
    const float* __restrict__ bih, const float* __restrict__ bhh,
    const short* __restrict__ whi,
    float* __restrict__ msg, int* __restrict__ degi, int* __restrict__ dego, int ntiles) {
    __shared__ short xs[128 * 64];   // x fp16
    __shared__ short hs[128 * 64];   // h fp16
    __shared__ short wh_s[384 * 64]; // fp16 weights: rows 0..191 Wih, 192..383 Whh
    int tid = threadIdx.x;
    for (int i = 0; i < 6; ++i) {    // stage weights (3072 short8)
        int q = i * 512 + tid;
        short8 v = ((const short8*)whi)[q];
        int r = q >> 3; int kb = (q & 7) * 16;
        *(short8*)((char*)wh_s + r * 128 + swz(r, kb)) = v;
    }

    int lane = tid & 63, w = tid >> 6;
    int col = lane & 15, rgrp = lane >> 4;
    int rowb = w * 16;
    int arow = rowb + col;
    int kl = rgrp * 8;
    int el = tid >> 2; int d0s = (tid & 3) * 16;
    f32x4 z4 = {0.f, 0.f, 0.f, 0.f};
    float birv[4], bizv[4], binv[4], bhrv[4], bhzv[4], bhnv[4];
    for (int t = 0; t < 4; ++t) {
        int d = t * 16 + col;
        birv[t] = bih[d];       bhrv[t] = bhh[d];
        bizv[t] = bih[64 + d];  bhzv[t] = bhh[64 + d];
        binv[t] = bih[128 + d]; bhnv[t] = bhh[128 + d];
    }

    // prefetch registers (named, rule-#20-safe)
    f32x4 pa0, pa1, pa2, pa3, pr0, pr1, pr2, pr3, ph0, ph1, ph2, ph3;
    {   // prologue: load first tile
        int e = blockIdx.x * 128 + el;
        int et = etype[e]; int sv = src[e];
        const float* ef = efeat + (size_t)e * 64 + d0s;
        const float* re = rel_emb + et * 64 + d0s;
        const float* nf = nfeat + (size_t)sv * 64 + d0s;
        pa0 = *(const f32x4*)ef;       pa1 = *(const f32x4*)(ef + 4);
        pa2 = *(const f32x4*)(ef + 8); pa3 = *(const f32x4*)(ef + 12);
        pr0 = *(const f32x4*)re;       pr1 = *(const f32x4*)(re + 4);
        pr2 = *(const f32x4*)(re + 8); pr3 = *(const f32x4*)(re + 12);
        ph0 = *(const f32x4*)nf;       ph1 = *(const f32x4*)(nf + 4);
        ph2 = *(const f32x4*)(nf + 8); ph3 = *(const f32x4*)(nf + 12);
    }

    for (int tile = blockIdx.x; tile < ntiles; tile += gridDim.x) {
        int base = tile * 128;
        {   // LDS-write phase from prefetched regs
            short8 sx0, sx1, sh0, sh1;
            for (int j = 0; j < 4; ++j) {
                sx0[j] = f2h(pa0[j] + pr0[j]); sx0[4 + j] = f2h(pa1[j] + pr1[j]);
                sx1[j] = f2h(pa2[j] + pr2[j]); sx1[4 + j] = f2h(pa3[j] + pr3[j]);
                sh0[j] = f2h(ph0[j]);          sh0[4 + j] = f2h(ph1[j]);
                sh1[j] = f2h(ph2[j]);          sh1[4 + j] = f2h(ph3[j]);
            }
            int kb0 = d0s * 2, kb1 = (d0s + 8) * 2;
            *(short8*)((char*)xs + el * 128 + swz(el, kb0)) = sx0;
            *(short8*)((char*)xs + el * 128 + swz(el, kb1)) = sx1;
            *(short8*)((char*)hs + el * 128 + swz(el, kb0)) = sh0;
            *(short8*)((char*)hs + el * 128 + swz(el, kb1)) = sh1;
            if (tid < 128) {
                int e2 = base + tid;
                atomicAdd(&degi[dst[e2]], 1);
                atomicAdd(&dego[src[e2]], 1);
            }
        }
        __syncthreads();
        int nt = tile + gridDim.x;
        if (nt < ntiles) {   // prefetch next tile: latency hides under MFMA+epilogue
            int e = nt * 128 + el;
            int et = etype[e]; int sv = src[e];
            const float* ef = efeat + (size_t)e * 64 + d0s;
            const float* re = rel_emb + et * 64 + d0s;
            const float* nf = nfeat + (size_t)sv * 64 + d0s;
            pa0 = *(const f32x4*)ef;       pa1 = *(const f32x4*)(ef + 4);
            pa2 = *(const f32x4*)(ef + 8); pa3 = *(const f32x4*)(ef + 12);
            pr0 = *(const f32x4*)re;       pr1 = *(const f32x4*)(re + 4);
            pr2 = *(const f32x4*)(re + 8); pr3 = *(const f32x4*)(re + 12);
            ph0 = *(const f32x4*)nf;       ph1 = *(const f32x4*)(nf + 4);
            ph2 = *(const f32x4*)(nf + 8); ph3 = *(const f32x4*)(nf + 12);
        }

        f32x4 gi[12], gh[12];
        for (int t = 0; t < 12; ++t) { gi[t] = z4; gh[t] = z4; }
        __builtin_amdgcn_s_setprio(1);
        for (int ks = 0; ks < 2; ++ks) {
            int kb = (ks * 32 + kl) * 2;
            half8 xf = *(half8*)((char*)xs + arow * 128 + swz(arow, kb));
            half8 hf = *(half8*)((char*)hs + arow * 128 + swz(arow, kb));
#pragma unroll
            for (int ct = 0; ct < 12; ++ct) {
                int wr = ct * 16 + col;
                half8 wah = *(half8*)((char*)wh_s + wr * 128 + swz(wr, kb));
                half8 wbh = *(half8*)((char*)wh_s + (192 + wr) * 128 + swz(192 + wr, kb));
                gi[ct] = __builtin_amdgcn_mfma_f32_16x16x32_f16(xf, wah, gi[ct], 0, 0, 0);
                gh[ct] = __builtin_amdgcn_mfma_f32_16x16x32_f16(hf, wbh, gh[ct], 0, 0, 0);
            }
        }
        __builtin_amdgcn_s_setprio(0);
        __syncthreads();   // all LDS reads done; next iteration may overwrite

        int se[4];
        for (int j = 0; j < 4; ++j) se[j] = src[base + rowb + rgrp * 4 + j];
        for (int t = 0; t < 4; ++t) {
            int d = t * 16 + col;
            for (int j = 0; j < 4; ++j) {
                int el2 = rowb + rgrp * 4 + j;
                float hv = nfeat[(size_t)se[j] * 64 + d];   // fp32 exact (L2-hot)
                float r = sigm(gi[t][j] + birv[t] + gh[t][j] + bhrv[t]);
                float z = sigm(gi[t + 4][j] + bizv[t] + gh[t + 4][j] + bhzv[t]);
                float n = tanh_(gi[t + 8][j] + binv[t] + r * (gh[t + 8][j] + bhnv[t]));
                float m = (1.f - z) * n + z * hv;
                msg[(size_t)(base + el2) * 64 + d] = m;
            }
        }
    }
}

// ---------------- parallel exclusive scan of degi -> offs, cursor --------------
__global__ void k_scan1(const int* __restrict__ degi, int* __restrict__ bsum, int n) {
    __shared__ int red[256];
    int i = blockIdx.x * 256 + threadIdx.x;
    red[threadIdx.x] = (i < n) ? degi[i] : 0;
    __syncthreads();
    for (int off = 128; off > 0; off >>= 1) {
        if (threadIdx.x < off) red[threadIdx.x] += red[threadIdx.x + off];
        __syncthreads();
    }
    if (threadIdx.x == 0) bsum[blockIdx.x] = red[0];
}
__global__ void k_scan2(int* __restrict__ bsum, int nb) {
    __shared__ int part[1024];
    int tid = threadIdx.x;
    int orig = (tid < nb) ? bsum[tid] : 0;
    part[tid] = orig;
    __syncthreads();
    for (int off = 1; off < 1024; off <<= 1) {
        int t = (tid >= off) ? part[tid - off] : 0;
        __syncthreads();
        part[tid] += t;
        __syncthreads();
    }
    if (tid < nb) bsum[tid] = part[tid] - orig;   // exclusive block prefix
}
__global__ void k_scan3(const int* __restrict__ degi, const int* __restrict__ bsum,
                        int* __restrict__ offs, int* __restrict__ cursor, int n) {
    __shared__ int part[256];
    int tid = threadIdx.x;
    int i = blockIdx.x * 256 + tid;
    int v = (i < n) ? degi[i] : 0;
    part[tid] = v;
    __syncthreads();
    for (int off = 1; off < 256; off <<= 1) {
        int t = (tid >= off) ? part[tid - off] : 0;
        __syncthreads();
        part[tid] += t;
        __syncthreads();
    }
    int excl = part[tid] - v + bsum[blockIdx.x];
    if (i < n) { offs[i] = excl; cursor[i] = excl; }
    if (i == n - 1) offs[n] = excl + v;
}

// ---------------- scatter edge ids into CSR buckets ----------------
__global__ void k_scatter(const int* __restrict__ dst, int* __restrict__ cursor,
                          int* __restrict__ idx, int E) {
    int e = blockIdx.x * 256 + threadIdx.x;
    if (e < E) {
        int p = atomicAdd(&cursor[dst[e]], 1);
        idx[p] = e;
    }
}

// ---------------- avg log out-degree: deterministic two-stage reduction ----------
__global__ void k_avgd(const int* __restrict__ dego, float* __restrict__ partial, int n) {
    __shared__ float red[256];
    int i = blockIdx.x * blockDim.x + threadIdx.x;
    float s = 0.f;
    for (int k = i; k < n; k += gridDim.x * blockDim.x) s += __logf((float)dego[k] + 1.f);
    red[threadIdx.x] = s;
    __syncthreads();
    for (int off = 128; off > 0; off >>= 1) {
        if (threadIdx.x < off) red[threadIdx.x] += red[threadIdx.x + off];
        __syncthreads();
    }
    if (threadIdx.x == 0) partial[blockIdx.x] = red[0];
}
__global__ void k_avgd2(const float* __restrict__ partial, float* __restrict__ logsum, int m) {
    if (threadIdx.x == 0 && blockIdx.x == 0) {
        float s = 0.f;
        for (int i = 0; i < m; ++i) s += partial[i];   // fixed order -> deterministic
        *logsum = s;
    }
}

// ---------------- PNA: CSR gather stats (f64 sums), dual-resident weights, LN ------
__global__ __launch_bounds__(256, 1) void k_pna(
    const float* __restrict__ msg, const int* __restrict__ offs, const int* __restrict__ idx,
    const float* __restrict__ logsum,
    const short* __restrict__ wphi, const short* __restrict__ wplo,
    const float* __restrict__ pnab,
    const float* __restrict__ lng, const float* __restrict__ lnb,
    float* __restrict__ nfnew, float* __restrict__ out1, int N) {
    __shared__ short agg[64 * 256];
    __shared__ short agl[64 * 256];
    __shared__ short wp[64 * 256];   // hi weights
    __shared__ short wpl[64 * 256];  // lo weights (resident together -> no restage)
    __shared__ float scl[64];
    int tid = threadIdx.x; int nb = blockIdx.x * 64;
    float avgd = logsum[0] / (float)N;
    f32x4 z4 = {0.f, 0.f, 0.f, 0.f};
    {
        int il = tid >> 2; int node = nb + il; int d0 = (tid & 3) * 16;
        if (node < N) {
            int o0 = offs[node], o1 = offs[node + 1];
            int dg = o1 - o0;
            double sm[16], sq[16];
            f32x4 mx[4], mn[4];
#pragma unroll
            for (int k = 0; k < 16; ++k) { sm[k] = 0.0; sq[k] = 0.0; }
#pragma unroll
            for (int q = 0; q < 4; ++q) {
                mx[q] = (f32x4){-1e30f, -1e30f, -1e30f, -1e30f};
                mn[q] = (f32x4){1e30f, 1e30f, 1e30f, 1e30f};
            }
            for (int i = o0; i < o1; ++i) {
                int e = idx[i];
                const float* mrow = msg + (size_t)e * 64 + d0;
#pragma unroll
                for (int q = 0; q < 4; ++q) {
                    f32x4 v = *(const f32x4*)(mrow + q * 4);
#pragma unroll
                    for (int j = 0; j < 4; ++j) {
                        double dv = (double)v[j];
                        sm[q * 4 + j] += dv;
                        sq[q * 4 + j] += dv * dv;
                        mx[q][j] = fmaxf(mx[q][j], v[j]);
                        mn[q][j] = fminf(mn[q][j], v[j]);
                    }
                }
            }
            double inv = 1.0 / (double)max(dg, 1);
            bool has = dg > 0;
            for (int g = 0; g < 2; ++g) {
                short8 vm, vx, vn, vs, lm, lx, ln_, ls;
                for (int k = 0; k < 8; ++k) {
                    int kk = g * 8 + k; int q = kk >> 2, j = kk & 3;
                    double mean_d = sm[kk] * inv;
                    double var_d = sq[kk] * inv - mean_d * mean_d;
                    float mean = (float)mean_d;
                    float sd = sqrtf(fmaxf((float)var_d, 0.f) + 1e-5f);
                    float mxv = has ? mx[q][j] : 0.f;
                    float mnv = has ? mn[q][j] : 0.f;
                    short th, tl;
                    split2h(mean, th, tl); vm[k] = th; lm[k] = tl;
                    split2h(mxv, th, tl);  vx[k] = th; lx[k] = tl;
                    split2h(mnv, th, tl);  vn[k] = th; ln_[k] = tl;
                    split2h(sd, th, tl);   vs[k] = th; ls[k] = tl;
                }
                int kb = (d0 + g * 8) * 2;
                *(short8*)((char*)agg + il * 512 + swz(il, kb)) = vm;
                *(short8*)((char*)agg + il * 512 + swz(il, kb + 128)) = vx;
                *(short8*)((char*)agg + il * 512 + swz(il, kb + 256)) = vn;
                *(short8*)((char*)agg + il * 512 + swz(il, kb + 384)) = vs;
                *(short8*)((char*)agl + il * 512 + swz(il, kb)) = lm;
                *(short8*)((char*)agl + il * 512 + swz(il, kb + 128)) = lx;
                *(short8*)((char*)agl + il * 512 + swz(il, kb + 256)) = ln_;
                *(short8*)((char*)agl + il * 512 + swz(il, kb + 384)) = ls;
            }
            if ((tid & 3) == 0) scl[il] = __logf((float)dg + 1.f) / avgd;
        } else {
            short8 zz = {0, 0, 0, 0, 0, 0, 0, 0};
            for (int g = 0; g < 2; ++g) {
                int kb = (d0 + g * 8) * 2;
                for (int part = 0; part < 4; ++part) {
                    *(short8*)((char*)agg + il * 512 + swz(il, kb + part * 128)) = zz;
                    *(short8*)((char*)agl + il * 512 + swz(il, kb + part * 128)) = zz;
                }
            }
            if ((tid & 3) == 0) scl[il] = 0.f;
        }
    }
    for (int i = 0; i < 8; ++i) {
        int q = i * 256 + tid;   // 2048 short8 each
        int r = q >> 5; int kb = (q & 31) * 16;
        short8 vh = ((const short8*)wphi)[q];
        short8 vl = ((const short8*)wplo)[q];
        *(short8*)((char*)wp + r * 512 + swz(r, kb)) = vh;
        *(short8*)((char*)wpl + r * 512 + swz(r, kb)) = vl;
    }
    __syncthreads();

    int lane = tid & 63, w = tid >> 6;
    int col = lane & 15, rgrp = lane >> 4;
    int arow = w * 16 + col; int kl = rgrp * 8;
    f32x4 acc[4] = {z4, z4, z4, z4};
    for (int ks = 0; ks < 8; ++ks) {   // (A_hi + A_lo)*W_hi + A_hi*W_lo
        int kb = (ks * 32 + kl) * 2;
        half8 af = *(half8*)((char*)agg + arow * 512 + swz(arow, kb));
        half8 al = *(half8*)((char*)agl + arow * 512 + swz(arow, kb));
#pragma unroll
        for (int ct = 0; ct < 4; ++ct) {
            int wr = ct * 16 + col;
            half8 bh_ = *(half8*)((char*)wp + wr * 512 + swz(wr, kb));
            half8 bl_ = *(half8*)((char*)wpl + wr * 512 + swz(wr, kb));
            acc[ct] = __builtin_amdgcn_mfma_f32_16x16x32_f16(af, bh_, acc[ct], 0, 0, 0);
            acc[ct] = __builtin_amdgcn_mfma_f32_16x16x32_f16(al, bh_, acc[ct], 0, 0, 0);
            acc[ct] = __builtin_amdgcn_mfma_f32_16x16x32_f16(af, bl_, acc[ct], 0, 0, 0);
        }
    }
    for (int j = 0; j < 4; ++j) {
        int il = w * 16 + rgrp * 4 + j; int node = nb + il;
        float sc = scl[il];
        float v[4]; float s = 0.f, s2 = 0.f;
        for (int ct = 0; ct < 4; ++ct) {
            int d = ct * 16 + col;
            float x = (acc[ct][j] + pnab[d]) * sc;
            v[ct] = x; s += x; s2 += x * x;
        }
        for (int m = 1; m < 16; m <<= 1) { s += __shfl_xor(s, m); s2 += __shfl_xor(s2, m); }
        float mean = s * (1.f / 64.f);
        float var = s2 * (1.f / 64.f) - mean * mean;
        float rstd = rsqrtf(var + 1e-5f);
        if (node < N) {
            for (int ct = 0; ct < 4; ++ct) {
                int d = ct * 16 + col;
                nfnew[(size_t)node * 64 + d] = v[ct];
                out1[(size_t)node * 64 + d] = (v[ct] - mean) * rstd * lng[d] + lnb[d];
            }
        }
    }
}

// ---------------- LSTM edge update + 2x LN ----------------
// persistent (512,1) grid 256, 128-edge tiles; fp16 weights resident; T14 prefetch
__global__ __launch_bounds__(512, 1) void k_lstm(
    const int* __restrict__ dst, const float* __restrict__ efeat, const float* __restrict__ equery,
    const float* __restrict__ nfnew,
    const short* __restrict__ wlhi,
    const float* __restrict__ bih, const float* __restrict__ bhh,
    const float* __restrict__ lng, const float* __restrict__ lnb,
    float* __restrict__ out0, float* __restrict__ out2, int ntiles) {
    __shared__ short ia[128 * 64];
    __shared__ short ea[128 * 64];
    __shared__ short wh_s[512 * 64];  // fp16: rows 0..255 Wih, 256..511 Whh
    int tid = threadIdx.x;
    for (int i = 0; i < 8; ++i) {
        int q = i * 512 + tid;   // 4096 short8
        short8 v = ((const short8*)wlhi)[q];
        int r = q >> 3; int kb = (q & 7) * 16;
        *(short8*)((char*)wh_s + r * 128 + swz(r, kb)) = v;
    }

    int lane = tid & 63, w = tid >> 6;
    int col = lane & 15, rgrp = lane >> 4;
    int arow = w * 16 + col; int kl = rgrp * 8;
    int el = tid >> 2; int d0s = (tid & 3) * 16;
    f32x4 z4 = {0.f, 0.f, 0.f, 0.f};
    float bsi[4], bsf[4], bsg[4], bso[4], lngv[4], lnbv[4];
    for (int t = 0; t < 4; ++t) {
        int d = t * 16 + col;
        bsi[t] = bih[d] + bhh[d];
        bsf[t] = bih[64 + d] + bhh[64 + d];
        bsg[t] = bih[128 + d] + bhh[128 + d];
        bso[t] = bih[192 + d] + bhh[192 + d];
        lngv[t] = lng[d]; lnbv[t] = lnb[d];
    }

    f32x4 pi0, pi1, pi2, pi3, pe0, pe1, pe2, pe3;   // named prefetch regs
    {   // prologue: load first tile
        int e = blockIdx.x * 128 + el;
        int dv = dst[e];
        const float* ip = nfnew + (size_t)dv * 64 + d0s;
        const float* ep = efeat + (size_t)e * 64 + d0s;
        pi0 = *(const f32x4*)ip;       pi1 = *(const f32x4*)(ip + 4);
        pi2 = *(const f32x4*)(ip + 8); pi3 = *(const f32x4*)(ip + 12);
        pe0 = *(const f32x4*)ep;       pe1 = *(const f32x4*)(ep + 4);
        pe2 = *(const f32x4*)(ep + 8); pe3 = *(const f32x4*)(ep + 12);
    }

    for (int tile = blockIdx.x; tile < ntiles; tile += gridDim.x) {
        int base = tile * 128;
        {   // LDS-write phase from prefetched regs
            short8 si0, si1, se0, se1;
            for (int j = 0; j < 4; ++j) {
                si0[j] = f2h(pi0[j]); si0[4 + j] = f2h(pi1[j]);
                si1[j] = f2h(pi2[j]); si1[4 + j] = f2h(pi3[j]);
                se0[j] = f2h(pe0[j]); se0[4 + j] = f2h(pe1[j]);
                se1[j] = f2h(pe2[j]); se1[4 + j] = f2h(pe3[j]);
            }
            int kb0 = d0s * 2, kb1 = (d0s + 8) * 2;
            *(short8*)((char*)ia + el * 128 + swz(el, kb0)) = si0;
            *(short8*)((char*)ia + el * 128 + swz(el, kb1)) = si1;
            *(short8*)((char*)ea + el * 128 + swz(el, kb0)) = se0;
            *(short8*)((char*)ea + el * 128 + swz(el, kb1)) = se1;
        }
        __syncthreads();
        int nt = tile + gridDim.x;
        if (nt < ntiles) {   // prefetch next tile
            int e = nt * 128 + el;
            int dv = dst[e];
            const float* ip = nfnew + (size_t)dv * 64 + d0s;
            const float* ep = efeat + (size_t)e * 64 + d0s;
            pi0 = *(const f32x4*)ip;       pi1 = *(const f32x4*)(ip + 4);
            pi2 = *(const f32x4*)(ip + 8); pi3 = *(const f32x4*)(ip + 12);
            pe0 = *(const f32x4*)ep;       pe1 = *(const f32x4*)(ep + 4);
            pe2 = *(const f32x4*)(ep + 8); pe3 = *(const f32x4*)(ep + 12);
        }

        f32x4 acc[16];
        for (int t = 0; t < 16; ++t) acc[t] = z4;
        __builtin_amdgcn_s_setprio(1);
        for (int ks = 0; ks < 2; ++ks) {
            int kb = (ks * 32 + kl) * 2;
            half8 fi = *(half8*)((char*)ia + arow * 128 + swz(arow, kb));
            half8 fe = *(half8*)((char*)ea + arow * 128 + swz(arow, kb));
#pragma unroll
            for (int ct = 0; ct < 16; ++ct) {
                int wr = ct * 16 + col;
                half8 wah = *(half8*)((char*)wh_s + wr * 128 + swz(wr, kb));
                half8 wbh = *(half8*)((char*)wh_s + (256 + wr) * 128 + swz(256 + wr, kb));
                acc[ct] = __builtin_amdgcn_mfma_f32_16x16x32_f16(fi, wah, acc[ct], 0, 0, 0);
                acc[ct] = __builtin_amdgcn_mfma_f32_16x16x32_f16(fe, wbh, acc[ct], 0, 0, 0);
            }
        }
        __builtin_amdgcn_s_setprio(0);
        __syncthreads();   // all waves done reading ia/ea -> next iteration may overwrite

        for (int j = 0; j < 4; ++j) {
            size_t e = base + w * 16 + rgrp * 4 + j;
            float hv[4], cv[4];
            float sh = 0.f, sh2 = 0.f, sc = 0.f, sc2 = 0.f;
            for (int t = 0; t < 4; ++t) {
                int d = t * 16 + col;
                float gi_ = acc[t][j] + bsi[t];
                float gf_ = acc[t + 4][j] + bsf[t];
                float gg_ = acc[t + 8][j] + bsg[t];
                float go_ = acc[t + 12][j] + bso[t];
                float eq = equery[e * 64 + d];
                float c = sigm(gf_) * eq + sigm(gi_) * tanh_(gg_);
                float h = sigm(go_) * tanh_(c);
                cv[t] = c; hv[t] = h;
                sh += h; sh2 += h * h; sc += c; sc2 += c * c;
            }
            for (int m = 1; m < 16; m <<= 1) {
                sh += __shfl_xor(sh, m); sh2 += __shfl_xor(sh2, m);
                sc += __shfl_xor(sc, m); sc2 += __shfl_xor(sc2, m);
            }
            float mh = sh * (1.f / 64.f), vh = sh2 * (1.f / 64.f) - mh * mh, rh = rsqrtf(vh + 1e-5f);
            float mc = sc * (1.f / 64.f), vc = sc2 * (1.f / 64.f) - mc * mc, rc = rsqrtf(vc + 1e-5f);
            for (int t = 0; t < 4; ++t) {
                int d = t * 16 + col;
                out0[e * 64 + d] = (hv[t] - mh) * rh * lngv[t] + lnbv[t];
                out2[e * 64 + d] = (cv[t] - mc) * rc * lngv[t] + lnbv[t];
            }
        }
    }
}

extern "C" void kernel_launch(void* const* d_in, const int* in_sizes, int n_in,
                              void* d_out, int out_size, void* d_ws, size_t ws_size,
                              hipStream_t stream) {
    const int* src = (const int*)d_in[0];
    const int* dst = (const int*)d_in[1];
    const int* etype = (const int*)d_in[2];
    const float* efeat = (const float*)d_in[3];
    const float* nfeat = (const float*)d_in[4];
    const float* equery = (const float*)d_in[5];
    const float* rel_emb = (const float*)d_in[6];
    const float* gWih = (const float*)d_in[7];
    const float* gWhh = (const float*)d_in[8];
    const float* gbih = (const float*)d_in[9];
    const float* gbhh = (const float*)d_in[10];
    const float* pW = (const float*)d_in[11];
    const float* pb = (const float*)d_in[12];
    const float* lWih = (const float*)d_in[13];
    const float* lWhh = (const float*)d_in[14];
    const float* lbih = (const float*)d_in[15];
    const float* lbhh = (const float*)d_in[16];
    const float* lng = (const float*)d_in[17];
    const float* lnb = (const float*)d_in[18];
    int E = in_sizes[0];
    int N = in_sizes[4] / 64;
    int ntiles = E / 128;
    int nb = (N + 255) / 256;

    char* p = (char*)d_ws;
    float* nfnew = (float*)p;     p += (size_t)N * 64 * 4;
    int* degi = (int*)p;          p += (size_t)N * 4;
    int* dego = (int*)p;          p += (size_t)N * 4;
    int* offs = (int*)p;          p += (size_t)(N + 1) * 4 + 252;  // keep 16B align downstream
    int* cursor = (int*)p;        p += (size_t)N * 4;
    int* idx = (int*)p;           p += (size_t)E * 4;
    float* logsum = (float*)p;    p += 256;
    float* partial = (float*)p;   p += 512;
    int* bsum = (int*)p;          p += 4096;
    short* wbf_hi = (short*)p;    p += 73728 * 2;
    short* wbf_lo = (short*)p;

    float* out0 = (float*)d_out;
    float* out1 = out0 + (size_t)E * 64;
    float* out2 = out1 + (size_t)N * 64;
    float* msg = out0;            // out0 region reused as msg scratch until k_lstm

    k_init<<<256, 256, 0, stream>>>(degi, dego, logsum, N);
    k_prep<<<288, 256, 0, stream>>>(gWih, gWhh, lWih, lWhh, pW, wbf_hi, wbf_lo);
    k_gru<<<256, 512, 0, stream>>>(src, dst, etype, efeat, nfeat, rel_emb, gbih, gbhh,
                                   wbf_hi, msg, degi, dego, ntiles);
    k_scan1<<<nb, 256, 0, stream>>>(degi, bsum, N);
    k_scan2<<<1, 1024, 0, stream>>>(bsum, nb);
    k_scan3<<<nb, 256, 0, stream>>>(degi, bsum, offs, cursor, N);
    k_scatter<<<(E + 255) / 256, 256, 0, stream>>>(dst, cursor, idx, E);
    k_avgd<<<128, 256, 0, stream>>>(dego, partial, N);
    k_avgd2<<<1, 64, 0, stream>>>(partial, logsum, 128);
    k_pna<<<(N + 63) / 64, 256, 0, stream>>>(msg, offs, idx, logsum,
                                             wbf_hi + 57344, wbf_lo + 57344, pb, lng, lnb,
                                             nfnew, out1, N);
    k_lstm<<<256, 512, 0, stream>>>(dst, efeat, equery, nfnew,
                                    wbf_hi + 24576,
                                    lbih, lbhh, lng, lnb, out0, out2, ntiles);
}

// Round 21
// 319.046 us; speedup vs baseline: 1.4259x; 1.0013x over previous
//
#include <hip/hip_runtime.h>
#include <hip/hip_bf16.h>

typedef __attribute__((ext_vector_type(8))) short short8;
typedef __attribute__((ext_vector_type(8))) _Float16 half8;
typedef __attribute__((ext_vector_type(4))) float f32x4;

#define DEV __device__ __forceinline__

DEV short f2h(float f) { _Float16 h = (_Float16)f; return __builtin_bit_cast(short, h); }
DEV float h2f(short s) { return (float)__builtin_bit_cast(_Float16, s); }
DEV void split2h(float v, short& hi, short& lo) {
    _Float16 h = (_Float16)v; hi = __builtin_bit_cast(short, h);
    _Float16 l = (_Float16)(v - (float)h); lo = __builtin_bit_cast(short, l);
}
DEV float frcp(float x) { return __builtin_amdgcn_rcpf(x); }          // v_rcp_f32, ~1 ulp
DEV float sigm(float x) { return frcp(1.f + __expf(-x)); }
DEV float tanh_(float x) { return 1.f - 2.f * frcp(__expf(2.f * x) + 1.f); }
DEV int swz(int r, int kb) { return kb ^ ((r & 7) << 4); }  // byte offset within row

// ---------------- init ----------------
__global__ void k_init(int* degi, int* dego, float* logsum, int n) {
    int i = blockIdx.x * blockDim.x + threadIdx.x;
    int st = gridDim.x * blockDim.x;
    for (int k = i; k < n; k += st) { degi[k] = 0; dego[k] = 0; }
    if (i == 0) *logsum = 0.f;
}

// ---------------- fp32 -> split fp16 (hi + lo residual) weight prep ----------------
// layout: [0,12288) gru_Wih | [12288,24576) gru_Whh | [24576,40960) lstm_Wih
//         [40960,57344) lstm_Whh | [57344,73728) pna_W
__global__ void k_prep(const float* __restrict__ a, const float* __restrict__ b,
                       const float* __restrict__ c, const float* __restrict__ d,
                       const float* __restrict__ e, short* __restrict__ ohi,
                       short* __restrict__ olo) {
    int i = blockIdx.x * 256 + threadIdx.x;
    float v;
    if (i < 12288) v = a[i];
    else if (i < 24576) v = b[i - 12288];
    else if (i < 40960) v = c[i - 24576];
    else if (i < 57344) v = d[i - 40960];
    else if (i < 73728) v = e[i - 57344];
    else return;
    short hi, lo; split2h(v, hi, lo);
    ohi[i] = hi; olo[i] = lo;
}

// ---------------- GRU messages -> msg[E][64] fp32, + degree counts ----------------
// persistent (512,1) grid 256, 128-edge tiles; fp16 weights resident; T14 prefetch
__global__ __launch_bounds__(512, 1) void k_gru(
    const int* __restrict__ src, const int* __restrict__ dst, const int* __restrict__ etype,
    const float* __restrict__ efeat, const float* __restrict__ nfeat, const float* __restrict__ rel_emb,
    const float* __restrict__ bih, const float* __restrict__ bhh,
    const short* __restrict__ whi,
    float* __restrict__ msg, int* __restrict__ degi, int* __restrict__ dego, int ntiles) {
    __shared__ short xs[128 * 64];   // x fp16
    __shared__ short hs[128 * 64];   // h fp16
    __shared__ short wh_s[384 * 64]; // fp16 weights: rows 0..191 Wih, 192..383 Whh
    int tid = threadIdx.x;
    for (int i = 0; i < 6; ++i) {    // stage weights (3072 short8)
        int q = i * 512 + tid;
        short8 v = ((const short8*)whi)[q];
        int r = q >> 3; int kb = (q & 7) * 16;
        *(short8*)((char*)wh_s + r * 128 + swz(r, kb)) = v;
    }

    int lane = tid & 63, w = tid >> 6;
    int col = lane & 15, rgrp = lane >> 4;
    int rowb = w * 16;
    int arow = rowb + col;
    int kl = rgrp * 8;
    int el = tid >> 2; int d0s = (tid & 3) * 16;
    f32x4 z4 = {0.f, 0.f, 0.f, 0.f};
    float birv[4], bizv[4], binv[4], bhrv[4], bhzv[4], bhnv[4];
    for (int t = 0; t < 4; ++t) {
        int d = t * 16 + col;
        birv[t] = bih[d];       bhrv[t] = bhh[d];
        bizv[t] = bih[64 + d];  bhzv[t] = bhh[64 + d];
        binv[t] = bih[128 + d]; bhnv[t] = bhh[128 + d];
    }

    // prefetch registers (named, rule-#20-safe)
    f32x4 pa0, pa1, pa2, pa3, pr0, pr1, pr2, pr3, ph0, ph1, ph2, ph3;
    {   // prologue: load first tile
        int e = blockIdx.x * 128 + el;
        int et = etype[e]; int sv = src[e];
        const float* ef = efeat + (size_t)e * 64 + d0s;
        const float* re = rel_emb + et * 64 + d0s;
        const float* nf = nfeat + (size_t)sv * 64 + d0s;
        pa0 = *(const f32x4*)ef;       pa1 = *(const f32x4*)(ef + 4);
        pa2 = *(const f32x4*)(ef + 8); pa3 = *(const f32x4*)(ef + 12);
        pr0 = *(const f32x4*)re;       pr1 = *(const f32x4*)(re + 4);
        pr2 = *(const f32x4*)(re + 8); pr3 = *(const f32x4*)(re + 12);
        ph0 = *(const f32x4*)nf;       ph1 = *(const f32x4*)(nf + 4);
        ph2 = *(const f32x4*)(nf + 8); ph3 = *(const f32x4*)(nf + 12);
    }

    for (int tile = blockIdx.x; tile < ntiles; tile += gridDim.x) {
        int base = tile * 128;
        {   // LDS-write phase from prefetched regs
            short8 sx0, sx1, sh0, sh1;
            for (int j = 0; j < 4; ++j) {
                sx0[j] = f2h(pa0[j] + pr0[j]); sx0[4 + j] = f2h(pa1[j] + pr1[j]);
                sx1[j] = f2h(pa2[j] + pr2[j]); sx1[4 + j] = f2h(pa3[j] + pr3[j]);
                sh0[j] = f2h(ph0[j]);          sh0[4 + j] = f2h(ph1[j]);
                sh1[j] = f2h(ph2[j]);          sh1[4 + j] = f2h(ph3[j]);
            }
            int kb0 = d0s * 2, kb1 = (d0s + 8) * 2;
            *(short8*)((char*)xs + el * 128 + swz(el, kb0)) = sx0;
            *(short8*)((char*)xs + el * 128 + swz(el, kb1)) = sx1;
            *(short8*)((char*)hs + el * 128 + swz(el, kb0)) = sh0;
            *(short8*)((char*)hs + el * 128 + swz(el, kb1)) = sh1;
            if (tid < 128) {
                int e2 = base + tid;
                atomicAdd(&degi[dst[e2]], 1);
                atomicAdd(&dego[src[e2]], 1);
            }
        }
        __syncthreads();
        int nt = tile + gridDim.x;
        if (nt < ntiles) {   // prefetch next tile: latency hides under MFMA+epilogue
            int e = nt * 128 + el;
            int et = etype[e]; int sv = src[e];
            const float* ef = efeat + (size_t)e * 64 + d0s;
            const float* re = rel_emb + et * 64 + d0s;
            const float* nf = nfeat + (size_t)sv * 64 + d0s;
            pa0 = *(const f32x4*)ef;       pa1 = *(const f32x4*)(ef + 4);
            pa2 = *(const f32x4*)(ef + 8); pa3 = *(const f32x4*)(ef + 12);
            pr0 = *(const f32x4*)re;       pr1 = *(const f32x4*)(re + 4);
            pr2 = *(const f32x4*)(re + 8); pr3 = *(const f32x4*)(re + 12);
            ph0 = *(const f32x4*)nf;       ph1 = *(const f32x4*)(nf + 4);
            ph2 = *(const f32x4*)(nf + 8); ph3 = *(const f32x4*)(nf + 12);
        }

        f32x4 gi[12], gh[12];
        for (int t = 0; t < 12; ++t) { gi[t] = z4; gh[t] = z4; }
        __builtin_amdgcn_s_setprio(1);
        for (int ks = 0; ks < 2; ++ks) {
            int kb = (ks * 32 + kl) * 2;
            half8 xf = *(half8*)((char*)xs + arow * 128 + swz(arow, kb));
            half8 hf = *(half8*)((char*)hs + arow * 128 + swz(arow, kb));
#pragma unroll
            for (int ct = 0; ct < 12; ++ct) {
                int wr = ct * 16 + col;
                half8 wah = *(half8*)((char*)wh_s + wr * 128 + swz(wr, kb));
                half8 wbh = *(half8*)((char*)wh_s + (192 + wr) * 128 + swz(192 + wr, kb));
                gi[ct] = __builtin_amdgcn_mfma_f32_16x16x32_f16(xf, wah, gi[ct], 0, 0, 0);
                gh[ct] = __builtin_amdgcn_mfma_f32_16x16x32_f16(hf, wbh, gh[ct], 0, 0, 0);
            }
        }
        __builtin_amdgcn_s_setprio(0);
        __syncthreads();   // all LDS reads done; next iteration may overwrite

        int se[4];
        for (int j = 0; j < 4; ++j) se[j] = src[base + rowb + rgrp * 4 + j];
        for (int t = 0; t < 4; ++t) {
            int d = t * 16 + col;
            for (int j = 0; j < 4; ++j) {
                int el2 = rowb + rgrp * 4 + j;
                float hv = nfeat[(size_t)se[j] * 64 + d];   // fp32 exact (L2-hot)
                float r = sigm(gi[t][j] + birv[t] + gh[t][j] + bhrv[t]);
                float z = sigm(gi[t + 4][j] + bizv[t] + gh[t + 4][j] + bhzv[t]);
                float n = tanh_(gi[t + 8][j] + binv[t] + r * (gh[t + 8][j] + bhnv[t]));
                float m = (1.f - z) * n + z * hv;
                msg[(size_t)(base + el2) * 64 + d] = m;
            }
        }
    }
}

// ---------------- parallel exclusive scan of degi -> offs, cursor --------------
__global__ void k_scan1(const int* __restrict__ degi, int* __restrict__ bsum, int n) {
    __shared__ int red[256];
    int i = blockIdx.x * 256 + threadIdx.x;
    red[threadIdx.x] = (i < n) ? degi[i] : 0;
    __syncthreads();
    for (int off = 128; off > 0; off >>= 1) {
        if (threadIdx.x < off) red[threadIdx.x] += red[threadIdx.x + off];
        __syncthreads();
    }
    if (threadIdx.x == 0) bsum[blockIdx.x] = red[0];
}
__global__ void k_scan2(int* __restrict__ bsum, int nb) {
    __shared__ int part[1024];
    int tid = threadIdx.x;
    int orig = (tid < nb) ? bsum[tid] : 0;
    part[tid] = orig;
    __syncthreads();
    for (int off = 1; off < 1024; off <<= 1) {
        int t = (tid >= off) ? part[tid - off] : 0;
        __syncthreads();
        part[tid] += t;
        __syncthreads();
    }
    if (tid < nb) bsum[tid] = part[tid] - orig;   // exclusive block prefix
}
__global__ void k_scan3(const int* __restrict__ degi, const int* __restrict__ bsum,
                        int* __restrict__ offs, int* __restrict__ cursor, int n) {
    __shared__ int part[256];
    int tid = threadIdx.x;
    int i = blockIdx.x * 256 + tid;
    int v = (i < n) ? degi[i] : 0;
    part[tid] = v;
    __syncthreads();
    for (int off = 1; off < 256; off <<= 1) {
        int t = (tid >= off) ? part[tid - off] : 0;
        __syncthreads();
        part[tid] += t;
        __syncthreads();
    }
    int excl = part[tid] - v + bsum[blockIdx.x];
    if (i < n) { offs[i] = excl; cursor[i] = excl; }
    if (i == n - 1) offs[n] = excl + v;
}

// ---------------- scatter edge ids into CSR buckets ----------------
__global__ void k_scatter(const int* __restrict__ dst, int* __restrict__ cursor,
                          int* __restrict__ idx, int E) {
    int e = blockIdx.x * 256 + threadIdx.x;
    if (e < E) {
        int p = atomicAdd(&cursor[dst[e]], 1);
        idx[p] = e;
    }
}

// ---------------- avg log out-degree: deterministic two-stage reduction ----------
__global__ void k_avgd(const int* __restrict__ dego, float* __restrict__ partial, int n) {
    __shared__ float red[256];
    int i = blockIdx.x * blockDim.x + threadIdx.x;
    float s = 0.f;
    for (int k = i; k < n; k += gridDim.x * blockDim.x) s += __logf((float)dego[k] + 1.f);
    red[threadIdx.x] = s;
    __syncthreads();
    for (int off = 128; off > 0; off >>= 1) {
        if (threadIdx.x < off) red[threadIdx.x] += red[threadIdx.x + off];
        __syncthreads();
    }
    if (threadIdx.x == 0) partial[blockIdx.x] = red[0];
}
__global__ void k_avgd2(const float* __restrict__ partial, float* __restrict__ logsum, int m) {
    if (threadIdx.x == 0 && blockIdx.x == 0) {
        float s = 0.f;
        for (int i = 0; i < m; ++i) s += partial[i];   // fixed order -> deterministic
        *logsum = s;
    }
}

// ---------------- PNA: CSR gather stats (f64 sums), dual-resident weights, LN ------
__global__ __launch_bounds__(256, 1) void k_pna(
    const float* __restrict__ msg, const int* __restrict__ offs, const int* __restrict__ idx,
    const float* __restrict__ logsum,
    const short* __restrict__ wphi, const short* __restrict__ wplo,
    const float* __restrict__ pnab,
    const float* __restrict__ lng, const float* __restrict__ lnb,
    float* __restrict__ nfnew, float* __restrict__ out1, int N) {
    __shared__ short agg[64 * 256];
    __shared__ short agl[64 * 256];
    __shared__ short wp[64 * 256];   // hi weights
    __shared__ short wpl[64 * 256];  // lo weights (resident together -> no restage)
    __shared__ float scl[64];
    int tid = threadIdx.x; int nb = blockIdx.x * 64;
    float avgd = logsum[0] / (float)N;
    f32x4 z4 = {0.f, 0.f, 0.f, 0.f};
    {
        int il = tid >> 2; int node = nb + il; int d0 = (tid & 3) * 16;
        if (node < N) {
            int o0 = offs[node], o1 = offs[node + 1];
            int dg = o1 - o0;
            double sm[16], sq[16];
            f32x4 mx[4], mn[4];
#pragma unroll
            for (int k = 0; k < 16; ++k) { sm[k] = 0.0; sq[k] = 0.0; }
#pragma unroll
            for (int q = 0; q < 4; ++q) {
                mx[q] = (f32x4){-1e30f, -1e30f, -1e30f, -1e30f};
                mn[q] = (f32x4){1e30f, 1e30f, 1e30f, 1e30f};
            }
            for (int i = o0; i < o1; ++i) {
                int e = idx[i];
                const float* mrow = msg + (size_t)e * 64 + d0;
#pragma unroll
                for (int q = 0; q < 4; ++q) {
                    f32x4 v = *(const f32x4*)(mrow + q * 4);
#pragma unroll
                    for (int j = 0; j < 4; ++j) {
                        double dv = (double)v[j];
                        sm[q * 4 + j] += dv;
                        sq[q * 4 + j] += dv * dv;
                        mx[q][j] = fmaxf(mx[q][j], v[j]);
                        mn[q][j] = fminf(mn[q][j], v[j]);
                    }
                }
            }
            double inv = 1.0 / (double)max(dg, 1);
            bool has = dg > 0;
            for (int g = 0; g < 2; ++g) {
                short8 vm, vx, vn, vs, lm, lx, ln_, ls;
                for (int k = 0; k < 8; ++k) {
                    int kk = g * 8 + k; int q = kk >> 2, j = kk & 3;
                    double mean_d = sm[kk] * inv;
                    double var_d = sq[kk] * inv - mean_d * mean_d;
                    float mean = (float)mean_d;
                    float sd = sqrtf(fmaxf((float)var_d, 0.f) + 1e-5f);
                    float mxv = has ? mx[q][j] : 0.f;
                    float mnv = has ? mn[q][j] : 0.f;
                    short th, tl;
                    split2h(mean, th, tl); vm[k] = th; lm[k] = tl;
                    split2h(mxv, th, tl);  vx[k] = th; lx[k] = tl;
                    split2h(mnv, th, tl);  vn[k] = th; ln_[k] = tl;
                    split2h(sd, th, tl);   vs[k] = th; ls[k] = tl;
                }
                int kb = (d0 + g * 8) * 2;
                *(short8*)((char*)agg + il * 512 + swz(il, kb)) = vm;
                *(short8*)((char*)agg + il * 512 + swz(il, kb + 128)) = vx;
                *(short8*)((char*)agg + il * 512 + swz(il, kb + 256)) = vn;
                *(short8*)((char*)agg + il * 512 + swz(il, kb + 384)) = vs;
                *(short8*)((char*)agl + il * 512 + swz(il, kb)) = lm;
                *(short8*)((char*)agl + il * 512 + swz(il, kb + 128)) = lx;
                *(short8*)((char*)agl + il * 512 + swz(il, kb + 256)) = ln_;
                *(short8*)((char*)agl + il * 512 + swz(il, kb + 384)) = ls;
            }
            if ((tid & 3) == 0) scl[il] = __logf((float)dg + 1.f) / avgd;
        } else {
            short8 zz = {0, 0, 0, 0, 0, 0, 0, 0};
            for (int g = 0; g < 2; ++g) {
                int kb = (d0 + g * 8) * 2;
                for (int part = 0; part < 4; ++part) {
                    *(short8*)((char*)agg + il * 512 + swz(il, kb + part * 128)) = zz;
                    *(short8*)((char*)agl + il * 512 + swz(il, kb + part * 128)) = zz;
                }
            }
            if ((tid & 3) == 0) scl[il] = 0.f;
        }
    }
    for (int i = 0; i < 8; ++i) {
        int q = i * 256 + tid;   // 2048 short8 each
        int r = q >> 5; int kb = (q & 31) * 16;
        short8 vh = ((const short8*)wphi)[q];
        short8 vl = ((const short8*)wplo)[q];
        *(short8*)((char*)wp + r * 512 + swz(r, kb)) = vh;
        *(short8*)((char*)wpl + r * 512 + swz(r, kb)) = vl;
    }
    __syncthreads();

    int lane = tid & 63, w = tid >> 6;
    int col = lane & 15, rgrp = lane >> 4;
    int arow = w * 16 + col; int kl = rgrp * 8;
    f32x4 acc[4] = {z4, z4, z4, z4};
    for (int ks = 0; ks < 8; ++ks) {   // (A_hi + A_lo)*W_hi + A_hi*W_lo
        int kb = (ks * 32 + kl) * 2;
        half8 af = *(half8*)((char*)agg + arow * 512 + swz(arow, kb));
        half8 al = *(half8*)((char*)agl + arow * 512 + swz(arow, kb));
#pragma unroll
        for (int ct = 0; ct < 4; ++ct) {
            int wr = ct * 16 + col;
            half8 bh_ = *(half8*)((char*)wp + wr * 512 + swz(wr, kb));
            half8 bl_ = *(half8*)((char*)wpl + wr * 512 + swz(wr, kb));
            acc[ct] = __builtin_amdgcn_mfma_f32_16x16x32_f16(af, bh_, acc[ct], 0, 0, 0);
            acc[ct] = __builtin_amdgcn_mfma_f32_16x16x32_f16(al, bh_, acc[ct], 0, 0, 0);
            acc[ct] = __builtin_amdgcn_mfma_f32_16x16x32_f16(af, bl_, acc[ct], 0, 0, 0);
        }
    }
    for (int j = 0; j < 4; ++j) {
        int il = w * 16 + rgrp * 4 + j; int node = nb + il;
        float sc = scl[il];
        float v[4]; float s = 0.f, s2 = 0.f;
        for (int ct = 0; ct < 4; ++ct) {
            int d = ct * 16 + col;
            float x = (acc[ct][j] + pnab[d]) * sc;
            v[ct] = x; s += x; s2 += x * x;
        }
        for (int m = 1; m < 16; m <<= 1) { s += __shfl_xor(s, m); s2 += __shfl_xor(s2, m); }
        float mean = s * (1.f / 64.f);
        float var = s2 * (1.f / 64.f) - mean * mean;
        float rstd = rsqrtf(var + 1e-5f);
        if (node < N) {
            for (int ct = 0; ct < 4; ++ct) {
                int d = ct * 16 + col;
                nfnew[(size_t)node * 64 + d] = v[ct];
                out1[(size_t)node * 64 + d] = (v[ct] - mean) * rstd * lng[d] + lnb[d];
            }
        }
    }
}

// ---------------- LSTM edge update + 2x LN ----------------
// persistent (512,1) grid 256, 128-edge tiles; fp16 weights resident; T14 prefetch
__global__ __launch_bounds__(512, 1) void k_lstm(
    const int* __restrict__ dst, const float* __restrict__ efeat, const float* __restrict__ equery,
    const float* __restrict__ nfnew,
    const short* __restrict__ wlhi,
    const float* __restrict__ bih, const float* __restrict__ bhh,
    const float* __restrict__ lng, const float* __restrict__ lnb,
    float* __restrict__ out0, float* __restrict__ out2, int ntiles) {
    __shared__ short ia[128 * 64];
    __shared__ short ea[128 * 64];
    __shared__ short wh_s[512 * 64];  // fp16: rows 0..255 Wih, 256..511 Whh
    int tid = threadIdx.x;
    for (int i = 0; i < 8; ++i) {
        int q = i * 512 + tid;   // 4096 short8
        short8 v = ((const short8*)wlhi)[q];
        int r = q >> 3; int kb = (q & 7) * 16;
        *(short8*)((char*)wh_s + r * 128 + swz(r, kb)) = v;
    }

    int lane = tid & 63, w = tid >> 6;
    int col = lane & 15, rgrp = lane >> 4;
    int arow = w * 16 + col; int kl = rgrp * 8;
    int el = tid >> 2; int d0s = (tid & 3) * 16;
    f32x4 z4 = {0.f, 0.f, 0.f, 0.f};
    float bsi[4], bsf[4], bsg[4], bso[4], lngv[4], lnbv[4];
    for (int t = 0; t < 4; ++t) {
        int d = t * 16 + col;
        bsi[t] = bih[d] + bhh[d];
        bsf[t] = bih[64 + d] + bhh[64 + d];
        bsg[t] = bih[128 + d] + bhh[128 + d];
        bso[t] = bih[192 + d] + bhh[192 + d];
        lngv[t] = lng[d]; lnbv[t] = lnb[d];
    }

    f32x4 pi0, pi1, pi2, pi3, pe0, pe1, pe2, pe3;   // named prefetch regs
    {   // prologue: load first tile
        int e = blockIdx.x * 128 + el;
        int dv = dst[e];
        const float* ip = nfnew + (size_t)dv * 64 + d0s;
        const float* ep = efeat + (size_t)e * 64 + d0s;
        pi0 = *(const f32x4*)ip;       pi1 = *(const f32x4*)(ip + 4);
        pi2 = *(const f32x4*)(ip + 8); pi3 = *(const f32x4*)(ip + 12);
        pe0 = *(const f32x4*)ep;       pe1 = *(const f32x4*)(ep + 4);
        pe2 = *(const f32x4*)(ep + 8); pe3 = *(const f32x4*)(ep + 12);
    }

    for (int tile = blockIdx.x; tile < ntiles; tile += gridDim.x) {
        int base = tile * 128;
        {   // LDS-write phase from prefetched regs
            short8 si0, si1, se0, se1;
            for (int j = 0; j < 4; ++j) {
                si0[j] = f2h(pi0[j]); si0[4 + j] = f2h(pi1[j]);
                si1[j] = f2h(pi2[j]); si1[4 + j] = f2h(pi3[j]);
                se0[j] = f2h(pe0[j]); se0[4 + j] = f2h(pe1[j]);
                se1[j] = f2h(pe2[j]); se1[4 + j] = f2h(pe3[j]);
            }
            int kb0 = d0s * 2, kb1 = (d0s + 8) * 2;
            *(short8*)((char*)ia + el * 128 + swz(el, kb0)) = si0;
            *(short8*)((char*)ia + el * 128 + swz(el, kb1)) = si1;
            *(short8*)((char*)ea + el * 128 + swz(el, kb0)) = se0;
            *(short8*)((char*)ea + el * 128 + swz(el, kb1)) = se1;
        }
        __syncthreads();
        int nt = tile + gridDim.x;
        if (nt < ntiles) {   // prefetch next tile
            int e = nt * 128 + el;
            int dv = dst[e];
            const float* ip = nfnew + (size_t)dv * 64 + d0s;
            const float* ep = efeat + (size_t)e * 64 + d0s;
            pi0 = *(const f32x4*)ip;       pi1 = *(const f32x4*)(ip + 4);
            pi2 = *(const f32x4*)(ip + 8); pi3 = *(const f32x4*)(ip + 12);
            pe0 = *(const f32x4*)ep;       pe1 = *(const f32x4*)(ep + 4);
            pe2 = *(const f32x4*)(ep + 8); pe3 = *(const f32x4*)(ep + 12);
        }

        f32x4 acc[16];
        for (int t = 0; t < 16; ++t) acc[t] = z4;
        __builtin_amdgcn_s_setprio(1);
        for (int ks = 0; ks < 2; ++ks) {
            int kb = (ks * 32 + kl) * 2;
            half8 fi = *(half8*)((char*)ia + arow * 128 + swz(arow, kb));
            half8 fe = *(half8*)((char*)ea + arow * 128 + swz(arow, kb));
#pragma unroll
            for (int ct = 0; ct < 16; ++ct) {
                int wr = ct * 16 + col;
                half8 wah = *(half8*)((char*)wh_s + wr * 128 + swz(wr, kb));
                half8 wbh = *(half8*)((char*)wh_s + (256 + wr) * 128 + swz(256 + wr, kb));
                acc[ct] = __builtin_amdgcn_mfma_f32_16x16x32_f16(fi, wah, acc[ct], 0, 0, 0);
                acc[ct] = __builtin_amdgcn_mfma_f32_16x16x32_f16(fe, wbh, acc[ct], 0, 0, 0);
            }
        }
        __builtin_amdgcn_s_setprio(0);
        __syncthreads();   // all waves done reading ia/ea -> next iteration may overwrite

        for (int j = 0; j < 4; ++j) {
            size_t e = base + w * 16 + rgrp * 4 + j;
            float hv[4], cv[4];
            float sh = 0.f, sh2 = 0.f, sc = 0.f, sc2 = 0.f;
            for (int t = 0; t < 4; ++t) {
                int d = t * 16 + col;
                float gi_ = acc[t][j] + bsi[t];
                float gf_ = acc[t + 4][j] + bsf[t];
                float gg_ = acc[t + 8][j] + bsg[t];
                float go_ = acc[t + 12][j] + bso[t];
                float eq = equery[e * 64 + d];
                float c = sigm(gf_) * eq + sigm(gi_) * tanh_(gg_);
                float h = sigm(go_) * tanh_(c);
                cv[t] = c; hv[t] = h;
                sh += h; sh2 += h * h; sc += c; sc2 += c * c;
            }
            for (int m = 1; m < 16; m <<= 1) {
                sh += __shfl_xor(sh, m); sh2 += __shfl_xor(sh2, m);
                sc += __shfl_xor(sc, m); sc2 += __shfl_xor(sc2, m);
            }
            float mh = sh * (1.f / 64.f), vh = sh2 * (1.f / 64.f) - mh * mh, rh = rsqrtf(vh + 1e-5f);
            float mc = sc * (1.f / 64.f), vc = sc2 * (1.f / 64.f) - mc * mc, rc = rsqrtf(vc + 1e-5f);
            for (int t = 0; t < 4; ++t) {
                int d = t * 16 + col;
                out0[e * 64 + d] = (hv[t] - mh) * rh * lngv[t] + lnbv[t];
                out2[e * 64 + d] = (cv[t] - mc) * rc * lngv[t] + lnbv[t];
            }
        }
    }
}

extern "C" void kernel_launch(void* const* d_in, const int* in_sizes, int n_in,
                              void* d_out, int out_size, void* d_ws, size_t ws_size,
                              hipStream_t stream) {
    const int* src = (const int*)d_in[0];
    const int* dst = (const int*)d_in[1];
    const int* etype = (const int*)d_in[2];
    const float* efeat = (const float*)d_in[3];
    const float* nfeat = (const float*)d_in[4];
    const float* equery = (const float*)d_in[5];
    const float* rel_emb = (const float*)d_in[6];
    const float* gWih = (const float*)d_in[7];
    const float* gWhh = (const float*)d_in[8];
    const float* gbih = (const float*)d_in[9];
    const float* gbhh = (const float*)d_in[10];
    const float* pW = (const float*)d_in[11];
    const float* pb = (const float*)d_in[12];
    const float* lWih = (const float*)d_in[13];
    const float* lWhh = (const float*)d_in[14];
    const float* lbih = (const float*)d_in[15];
    const float* lbhh = (const float*)d_in[16];
    const float* lng = (const float*)d_in[17];
    const float* lnb = (const float*)d_in[18];
    int E = in_sizes[0];
    int N = in_sizes[4] / 64;
    int ntiles = E / 128;
    int nb = (N + 255) / 256;

    char* p = (char*)d_ws;
    float* nfnew = (float*)p;     p += (size_t)N * 64 * 4;
    int* degi = (int*)p;          p += (size_t)N * 4;
    int* dego = (int*)p;          p += (size_t)N * 4;
    int* offs = (int*)p;          p += (size_t)(N + 1) * 4 + 252;  // keep 16B align downstream
    int* cursor = (int*)p;        p += (size_t)N * 4;
    int* idx = (int*)p;           p += (size_t)E * 4;
    float* logsum = (float*)p;    p += 256;
    float* partial = (float*)p;   p += 512;
    int* bsum = (int*)p;          p += 4096;
    short* wbf_hi = (short*)p;    p += 73728 * 2;
    short* wbf_lo = (short*)p;

    float* out0 = (float*)d_out;
    float* out1 = out0 + (size_t)E * 64;
    float* out2 = out1 + (size_t)N * 64;
    float* msg = out0;            // out0 region reused as msg scratch until k_lstm

    k_init<<<256, 256, 0, stream>>>(degi, dego, logsum, N);
    k_prep<<<288, 256, 0, stream>>>(gWih, gWhh, lWih, lWhh, pW, wbf_hi, wbf_lo);
    k_gru<<<256, 512, 0, stream>>>(src, dst, etype, efeat, nfeat, rel_emb, gbih, gbhh,
                                   wbf_hi, msg, degi, dego, ntiles);
    k_scan1<<<nb, 256, 0, stream>>>(degi, bsum, N);
    k_scan2<<<1, 1024, 0, stream>>>(bsum, nb);
    k_scan3<<<nb, 256, 0, stream>>>(degi, bsum, offs, cursor, N);
    k_scatter<<<(E + 255) / 256, 256, 0, stream>>>(dst, cursor, idx, E);
    k_avgd<<<128, 256, 0, stream>>>(dego, partial, N);
    k_avgd2<<<1, 64, 0, stream>>>(partial, logsum, 128);
    k_pna<<<(N + 63) / 64, 256, 0, stream>>>(msg, offs, idx, logsum,
                                             wbf_hi + 57344, wbf_lo + 57344, pb, lng, lnb,
                                             nfnew, out1, N);
    k_lstm<<<256, 512, 0, stream>>>(dst, efeat, equery, nfnew,
                                    wbf_hi + 24576,
                                    lbih, lbhh, lng, lnb, out0, out2, ntiles);
}